// Round 7
// baseline (224.940 us; speedup 1.0000x reference)
//
#include <hip/hip_runtime.h>
#include <hip/hip_bf16.h>

#define N_NODES 50000
#define N_EDGES 800000
#define ET (N_EDGES + N_NODES)   // with self-loops
#define F_IN 128
#define HH 128                   // HEADS*HID
#define HEADS 4
#define HID 32
#define NCLS 16
#define NEG 0.2f
#define CAP 96                   // bucket capacity; deg ~ 1+Pois(16), max<<96
#define CSTR 16                  // counter stride (ints): 1 counter per 64-B line

#define PSH 9                            // partition = 512 consecutive dst nodes
#define NPART ((N_NODES + 511) >> PSH)   // 98
#define PCAP 12288                       // slots/partition (mean 8704, +38 sigma)
#define EPB 2048                         // edges per partition block
#define PB ((ET + EPB - 1) / EPB)        // 416 partition blocks
#define GB ((N_NODES + 63) / 64)         // 782 gemm blocks

typedef unsigned short u16;
typedef short bf16x8 __attribute__((ext_vector_type(8)));
typedef float f32x4 __attribute__((ext_vector_type(4)));
typedef u16 u16x8 __attribute__((ext_vector_type(8)));

__device__ __forceinline__ float lrelu(float x) { return x > 0.f ? x : NEG * x; }
__device__ __forceinline__ float bu2f(u16 u) { return __uint_as_float(((unsigned)u) << 16); }
__device__ __forceinline__ u16 f2bu(float f) {
    __hip_bfloat16 h = __float2bfloat16(f);
    return *reinterpret_cast<u16*>(&h);
}

__device__ __forceinline__ void edge_sd(const int* __restrict__ ei, int i, int& s, int& d) {
    if (i < N_EDGES) { s = ei[i]; d = ei[N_EDGES + i]; }
    else             { s = i - N_EDGES; d = s; }
}

// ---------------- fused: dst-partition binning + layer-1 GEMM via MFMA --------
// Partition role: bin edges by dst>>9 into packed per-partition lists (coalesced
// ~64-B runs) so the later bucket scatter has a 96-KB L2-resident window.
__global__ void __launch_bounds__(256) k_part_gemm1(
        const int* __restrict__ ei, int* __restrict__ pcur, unsigned* __restrict__ pbuf,
        const float* __restrict__ x, const float* __restrict__ W1,
        const float* __restrict__ a_s, const float* __restrict__ a_d,
        u16* __restrict__ h1b, float* __restrict__ al_s, float* __restrict__ al_d) {
    __shared__ u16 w1t[128 * 136];   // gemm: w1t[n][k] stride 136; part role reuses as raw LDS
    int bid = blockIdx.x;
    int t = threadIdx.x;
    bool is_part = (bid < 2 * PB) && ((bid & 1) == 0);
    if (is_part) {
        // -------- partition role (block fid = bid>>1, 2048 edges) --------
        unsigned* pcnt  = (unsigned*)w1t;   // [128] per-partition counts
        unsigned* pscan = pcnt + 128;       // [128] inclusive scan
        unsigned* gbase = pscan + 128;      // [128] global base cursors
        unsigned* eb    = gbase + 128;      // [2048] staged packed edges (9.75 KB total)
        int fid = bid >> 1;
        int base = fid * EPB;
        int count = min(EPB, ET - base);
        if (t < 128) pcnt[t] = 0;
        __syncthreads();
        int s[8], d[8], r[8], p[8];
        bool v[8];
#pragma unroll
        for (int k = 0; k < 8; ++k) {
            int i = base + k * 256 + t;
            v[k] = i < ET;
            if (v[k]) {
                edge_sd(ei, i, s[k], d[k]);
                p[k] = d[k] >> PSH;
                r[k] = (int)atomicAdd(&pcnt[p[k]], 1u);
            }
        }
        __syncthreads();
        if (t < 128) pscan[t] = pcnt[t];
        __syncthreads();
        for (int st = 1; st < 128; st <<= 1) {   // Hillis-Steele inclusive scan
            unsigned add = 0;
            if (t < 128 && t >= st) add = pscan[t - st];
            __syncthreads();
            if (t < 128) pscan[t] += add;
            __syncthreads();
        }
        if (t < 128) gbase[t] = pcnt[t] ? (unsigned)atomicAdd(&pcur[t * CSTR], (int)pcnt[t]) : 0u;
        __syncthreads();
#pragma unroll
        for (int k = 0; k < 8; ++k)
            if (v[k]) eb[(pscan[p[k]] - pcnt[p[k]]) + r[k]] =
                          ((unsigned)d[k] << 16) | (unsigned)s[k];
        __syncthreads();
        for (int j = t; j < count; j += 256) {
            unsigned val = eb[j];
            int pp = (int)(val >> (16 + PSH));
            unsigned gi = gbase[pp] + ((unsigned)j - (pscan[pp] - pcnt[pp]));
            if (gi < PCAP) pbuf[(size_t)pp * PCAP + gi] = val;
        }
        return;
    }
    // -------- gemm role --------
    int q = (bid < 2 * PB) ? (bid >> 1) : (bid - PB);
    for (int it = 0; it < 64; ++it) {
        int idx = it * 256 + t;              // idx = k*128 + n
        int k = idx >> 7, n = idx & 127;
        w1t[n * 136 + k] = f2bu(W1[idx]);
    }
    __syncthreads();
    int wave = t >> 6, lane = t & 63;
    int col = lane & 15, quad = lane >> 4;
    int tb = q * 64 + wave * 16;
    union { bf16x8 v; u16 u[8]; } af[4];
    int anode = tb + col;
    bool aval = anode < N_NODES;
    const float* xr = x + (size_t)anode * F_IN + quad * 8;
#pragma unroll
    for (int kb = 0; kb < 4; ++kb) {
        float4 lo = aval ? ((const float4*)(xr + kb * 32))[0] : make_float4(0.f, 0.f, 0.f, 0.f);
        float4 hi = aval ? ((const float4*)(xr + kb * 32))[1] : make_float4(0.f, 0.f, 0.f, 0.f);
        af[kb].u[0] = f2bu(lo.x); af[kb].u[1] = f2bu(lo.y);
        af[kb].u[2] = f2bu(lo.z); af[kb].u[3] = f2bu(lo.w);
        af[kb].u[4] = f2bu(hi.x); af[kb].u[5] = f2bu(hi.y);
        af[kb].u[6] = f2bu(hi.z); af[kb].u[7] = f2bu(hi.w);
    }
    float ps[4][4] = {}, pd[4][4] = {};
#pragma unroll
    for (int nt = 0; nt < 8; ++nt) {
        f32x4 acc = {0.f, 0.f, 0.f, 0.f};
#pragma unroll
        for (int kb = 0; kb < 4; ++kb) {
            bf16x8 bf = *(const bf16x8*)&w1t[(nt * 16 + col) * 136 + kb * 32 + quad * 8];
            acc = __builtin_amdgcn_mfma_f32_16x16x32_bf16(af[kb].v, bf, acc, 0, 0, 0);
        }
        int feat = nt * 16 + col;
        float asv = a_s[feat], adv = a_d[feat];
        const int head = nt >> 1;
#pragma unroll
        for (int rr = 0; rr < 4; ++rr) {
            int node = tb + quad * 4 + rr;
            float v = acc[rr];
            if (node < N_NODES) h1b[(size_t)node * HH + feat] = f2bu(v);
            ps[rr][head] = fmaf(v, asv, ps[rr][head]);
            pd[rr][head] = fmaf(v, adv, pd[rr][head]);
        }
    }
#pragma unroll
    for (int rr = 0; rr < 4; ++rr)
#pragma unroll
        for (int h = 0; h < 4; ++h)
#pragma unroll
            for (int w = 1; w < 16; w <<= 1) {
                ps[rr][h] += __shfl_xor(ps[rr][h], w);
                pd[rr][h] += __shfl_xor(pd[rr][h], w);
            }
    if (col == 0) {
#pragma unroll
        for (int rr = 0; rr < 4; ++rr) {
            int node = tb + quad * 4 + rr;
            if (node < N_NODES) {
#pragma unroll
                for (int h = 0; h < 4; ++h) {
                    al_s[node * 4 + h] = ps[rr][h];
                    al_d[node * 4 + h] = pd[rr][h];
                }
            }
        }
    }
}

// ---------------- stage 2: replay partitions into buckets (L2-resident window) ----
__global__ void __launch_bounds__(512) k_fill2(
        const int* __restrict__ pcur, const unsigned* __restrict__ pbuf,
        int* __restrict__ cnt, u16* __restrict__ esrc) {
    int p = blockIdx.x;
    int nE = min(pcur[p * CSTR], PCAP);
    const unsigned* pb = pbuf + (size_t)p * PCAP;
    for (int i = threadIdx.x; i < nE; i += 512) {
        unsigned v = pb[i];
        int d = (int)(v >> 16), s = (int)(v & 0xffffu);
        int pos = atomicAdd(&cnt[d * CSTR], 1);
        if (pos < CAP) esrc[d * CAP + pos] = (u16)s;
    }
}

// ---------------- layer 1 aggregate + fused layer-2 GEMM + layer-2 logits ----------------
__global__ void __launch_bounds__(256) k_agg1(
        const u16* __restrict__ esrc, const int* __restrict__ cnt,
        const float* __restrict__ alS, const float* __restrict__ alD,
        const u16* __restrict__ h1b, const float* __restrict__ b1,
        const float* __restrict__ W2, const float* __restrict__ a_s2,
        const float* __restrict__ a_d2,
        u16* __restrict__ h2b, float* __restrict__ alS2, float* __restrict__ alD2) {
    __shared__ float wls[4][CAP * HEADS];        // 6 KB
    __shared__ int   sls[4][CAP];                // 1.5 KB
    __shared__ __align__(16) float rowf[4][HH];  // 2 KB
    __shared__ float w2t[NCLS * 132];            // 8.25 KB
    __shared__ float as2s[NCLS], ad2s[NCLS];
    int t = threadIdx.x;
    for (int idx = t; idx < F_IN * NCLS; idx += 256) {
        int f = idx >> 4, c = idx & 15;
        w2t[c * 132 + f] = W2[idx];
    }
    if (t < NCLS) { as2s[t] = a_s2[t]; ad2s[t] = a_d2[t]; }
    __syncthreads();
    int wave = t >> 6, lane = t & 63;
    int n = blockIdx.x * 4 + wave;               // grid = N/4 exactly
    int off = n * CAP;
    int deg = min(cnt[n * CSTR], CAP);           // deg >= 1 (self-loop)
    int dm1 = deg - 1;
    // ---- 1) single coalesced esrc read; sources live in registers (sreg) ----
    int sreg = (int)esrc[off + min(lane, dm1)];
    if (lane < deg) sls[wave][lane] = sreg;                 // covers e < 64
    for (int e = 64 + lane; e < deg; e += 64)               // deg > 64: ~never
        sls[wave][e] = (int)esrc[off + e];
    // ---- 2) phase-B deep prefetch: up to 6 x 4 edges, exec-masked (no dup loads) ----
    int quarter = lane >> 4, fl = lane & 15;
    int hb = fl >> 2;
    u16x8 qf[6];
#pragma unroll
    for (int d = 0; d < 6; ++d) {
        int ee = quarter + 4 * d;
        int sp = __shfl(sreg, ee);                          // full-wave shfl; ee < 24 < 64
        if (ee < deg) qf[d] = ((const u16x8*)(h1b + (size_t)sp * HH))[fl];
    }
    // ---- 3) phase A: both alS gathers issued in parallel, exec-masked ----
    int slot = lane & 15, h = lane >> 4;
    int s0 = __shfl(sreg, slot);
    int s1 = __shfl(sreg, slot + 16);
    float av0 = 0.f, av1 = 0.f;
    if (slot < deg)      av0 = alS[(size_t)s0 * 4 + h];
    if (slot + 16 < deg) av1 = alS[(size_t)s1 * 4 + h];
    float ad = alD[n * 4 + h];
    float den = 0.f;
    if (slot < deg) {
        float wv = __expf(lrelu(av0 + ad));
        wls[wave][slot * 4 + h] = wv; den += wv;
    }
    if (slot + 16 < deg) {
        float wv = __expf(lrelu(av1 + ad));
        wls[wave][(slot + 16) * 4 + h] = wv; den += wv;
    }
    for (int e = slot + 32; e < deg; e += 16) {             // rare tail (P ~ 0.1%)
        int s = (int)esrc[off + e];
        float av = alS[(size_t)s * 4 + h];
        float wv = __expf(lrelu(av + ad));
        wls[wave][e * 4 + h] = wv; den += wv;
    }
#pragma unroll
    for (int w = 1; w < 16; w <<= 1) den += __shfl_xor(den, w);
    float inv = 1.f / den;
    // ---- 4) phase B consume: prefetched 24, then rare chained tail ----
    float invh = __shfl(inv, hb << 4);
    float acc[8] = {};
#pragma unroll
    for (int d = 0; d < 6; ++d) {
        int e = quarter + 4 * d;
        if (e < deg) {
            float a = wls[wave][e * 4 + hb] * invh;
#pragma unroll
            for (int j = 0; j < 8; ++j)
                acc[j] = fmaf(bu2f(qf[d][j]), a, acc[j]);
        }
    }
    for (int e = quarter + 24; e < deg; e += 4) {           // deg > 24: ~10% of nodes
        int sp = sls[wave][e];
        float a = wls[wave][e * 4 + hb] * invh;
        u16x8 qq = ((const u16x8*)(h1b + (size_t)sp * HH))[fl];
#pragma unroll
        for (int j = 0; j < 8; ++j)
            acc[j] = fmaf(bu2f(qq[j]), a, acc[j]);
    }
#pragma unroll
    for (int j = 0; j < 8; ++j) {
        acc[j] += __shfl_xor(acc[j], 16);
        acc[j] += __shfl_xor(acc[j], 32);
    }
    if (quarter == 0) {
        const float4* b4 = (const float4*)b1;
        float4 blo = b4[fl * 2], bhi = b4[fl * 2 + 1];
        float v[8];
        v[0] = acc[0] + blo.x; v[1] = acc[1] + blo.y;
        v[2] = acc[2] + blo.z; v[3] = acc[3] + blo.w;
        v[4] = acc[4] + bhi.x; v[5] = acc[5] + bhi.y;
        v[6] = acc[6] + bhi.z; v[7] = acc[7] + bhi.w;
#pragma unroll
        for (int j = 0; j < 8; ++j) v[j] = v[j] > 0.f ? v[j] : __expf(v[j]) - 1.f;
        ((float4*)&rowf[wave][0])[fl * 2]     = make_float4(v[0], v[1], v[2], v[3]);
        ((float4*)&rowf[wave][0])[fl * 2 + 1] = make_float4(v[4], v[5], v[6], v[7]);
    }
    // fused gemm2 (same wave -> LDS RAW ordered): f = 4i+q conflict-free
    int c = lane & 15, qq2 = lane >> 4;
    float h2acc = 0.f;
#pragma unroll
    for (int i = 0; i < 32; ++i) {
        int f = i * 4 + qq2;
        h2acc = fmaf(rowf[wave][f], w2t[c * 132 + f], h2acc);
    }
    h2acc += __shfl_xor(h2acc, 16);
    h2acc += __shfl_xor(h2acc, 32);
    if (lane < 16) h2b[(size_t)n * NCLS + lane] = f2bu(h2acc);
    float rs = h2acc * as2s[c], rd = h2acc * ad2s[c];
#pragma unroll
    for (int w = 1; w < 16; w <<= 1) { rs += __shfl_xor(rs, w); rd += __shfl_xor(rd, w); }
    if (lane == 0) { alS2[n] = rs; alD2[n] = rd; }
}

// ---------------- layer 2 aggregate + bias + log_softmax -> out ----------------
__global__ void __launch_bounds__(256) k_agg2(
        const u16* __restrict__ esrc, const int* __restrict__ cnt,
        const float* __restrict__ alS2, const float* __restrict__ alD2,
        const u16* __restrict__ h2b, const float* __restrict__ b2,
        float* __restrict__ out) {
    __shared__ float wls[4][CAP];   // 1.5 KB
    __shared__ int   sls[4][CAP];   // 1.5 KB
    int wave = threadIdx.x >> 6, lane = threadIdx.x & 63;
    int n = blockIdx.x * 4 + wave;
    int off = n * CAP;
    int deg = min(cnt[n * CSTR], CAP);
    int dm1 = deg - 1;
    int sub = lane >> 3, cp = lane & 7;
    // ---- 1) single coalesced esrc read ----
    int sreg = (int)esrc[off + min(lane, dm1)];
    // ---- 2) phase-B deep prefetch: up to 4 x 8 edges, exec-masked ----
    unsigned qf[4];
#pragma unroll
    for (int d = 0; d < 4; ++d) {
        int ee = sub + 8 * d;
        int sp = __shfl(sreg, ee);                          // ee < 32 < 64
        if (ee < deg) qf[d] = ((const unsigned*)(h2b + (size_t)sp * NCLS))[cp];
    }
    // ---- 3) phase A: lane e = lane, exec-masked gather ----
    float av = 0.f;
    if (lane < deg) av = alS2[sreg];
    float ad = alD2[n];
    float den = 0.f;
    float wv = __expf(lrelu(av + ad));
    if (lane < deg) { wls[wave][lane] = wv; sls[wave][lane] = sreg; den = wv; }
    for (int e = 64 + lane; e < deg; e += 64) {             // deg > 64: ~never
        int s = (int)esrc[off + e];
        float a2 = alS2[s];
        float w2v = __expf(lrelu(a2 + ad));
        wls[wave][e] = w2v; sls[wave][e] = s; den += w2v;
    }
#pragma unroll
    for (int w = 1; w < 64; w <<= 1) den += __shfl_xor(den, w);
    float inv = 1.f / den;
    // ---- 4) phase B consume: prefetched 32, then rare chained tail ----
    float a0 = 0.f, a1 = 0.f;
#pragma unroll
    for (int d = 0; d < 4; ++d) {
        int e = sub + 8 * d;
        if (e < deg) {
            float al = wls[wave][e] * inv;
            a0 = fmaf(bu2f((u16)(qf[d] & 0xffffu)), al, a0);
            a1 = fmaf(bu2f((u16)(qf[d] >> 16)), al, a1);
        }
    }
    for (int e = sub + 32; e < deg; e += 8) {               // deg > 32: ~0.03%
        int s = sls[wave][e];
        float al = wls[wave][e] * inv;
        unsigned qq = ((const unsigned*)(h2b + (size_t)s * NCLS))[cp];
        a0 = fmaf(bu2f((u16)(qq & 0xffffu)), al, a0);
        a1 = fmaf(bu2f((u16)(qq >> 16)), al, a1);
    }
    a0 += __shfl_xor(a0, 8);  a1 += __shfl_xor(a1, 8);
    a0 += __shfl_xor(a0, 16); a1 += __shfl_xor(a1, 16);
    a0 += __shfl_xor(a0, 32); a1 += __shfl_xor(a1, 32);
    float v0 = a0 + b2[2 * cp], v1 = a1 + b2[2 * cp + 1];
    float mx = fmaxf(v0, v1);
#pragma unroll
    for (int w = 1; w < 8; w <<= 1) mx = fmaxf(mx, __shfl_xor(mx, w));
    float ex = __expf(v0 - mx) + __expf(v1 - mx);
#pragma unroll
    for (int w = 1; w < 8; w <<= 1) ex += __shfl_xor(ex, w);
    float lse = mx + __logf(ex);
    if (lane < 8) ((float2*)(out + (size_t)n * NCLS))[cp] = make_float2(v0 - lse, v1 - lse);
}

extern "C" void kernel_launch(void* const* d_in, const int* in_sizes, int n_in,
                              void* d_out, int out_size, void* d_ws, size_t ws_size,
                              hipStream_t stream) {
    const float* x   = (const float*)d_in[0];
    const int*   ei  = (const int*)d_in[1];
    const float* W1  = (const float*)d_in[2];
    const float* as1 = (const float*)d_in[3];
    const float* ad1 = (const float*)d_in[4];
    const float* b1  = (const float*)d_in[5];
    const float* W2  = (const float*)d_in[6];
    const float* as2 = (const float*)d_in[7];
    const float* ad2 = (const float*)d_in[8];
    const float* b2  = (const float*)d_in[9];
    float* out = (float*)d_out;
    char* ws = (char*)d_ws;

    u16*      h1b  = (u16*)     (ws);               // N*128 bf16 = 12.8 MB
    float*    alS1 = (float*)   (ws + 12800000);    // N*4
    float*    alD1 = (float*)   (ws + 13600000);    // N*4
    u16*      h2b  = (u16*)     (ws + 14400000);    // N*16 bf16 = 1.6 MB
    float*    alS2 = (float*)   (ws + 16000000);    // N
    float*    alD2 = (float*)   (ws + 16200000);    // N
    int*      cnt  = (int*)     (ws + 16400000);    // N*CSTR ints = 3.2 MB (line-padded)
    u16*      esrc = (u16*)     (ws + 19600000);    // N*CAP u16 = 9.6 MB
    int*      pcur = (int*)     (ws + 29200000);    // NPART*CSTR ints = 8 KB (line-padded)
    unsigned* pbuf = (unsigned*)(ws + 29220000);    // NPART*PCAP u32 = 4.8 MB (total ~34 MB)

    hipMemsetAsync(cnt, 0, (size_t)N_NODES * CSTR * 4, stream);
    hipMemsetAsync(pcur, 0, (size_t)NPART * CSTR * 4, stream);
    k_part_gemm1<<<PB + GB, 256, 0, stream>>>(ei, pcur, pbuf,
                                              x, W1, as1, ad1, h1b, alS1, alD1);
    k_fill2<<<NPART, 512, 0, stream>>>(pcur, pbuf, cnt, esrc);
    k_agg1<<<N_NODES / 4, 256, 0, stream>>>(esrc, cnt, alS1, alD1, h1b, b1,
                                            W2, as2, ad2, h2b, alS2, alD2);
    k_agg2<<<N_NODES / 4, 256, 0, stream>>>(esrc, cnt, alS2, alD2, h2b, b2, out);
}

// Round 8
// 208.926 us; speedup vs baseline: 1.0766x; 1.0766x over previous
//
#include <hip/hip_runtime.h>
#include <hip/hip_bf16.h>

#define N_NODES 50000
#define N_EDGES 800000
#define ET (N_EDGES + N_NODES)   // with self-loops
#define F_IN 128
#define HH 128                   // HEADS*HID
#define HEADS 4
#define HID 32
#define NCLS 16
#define NEG 0.2f
#define CAP 96                   // bucket capacity; deg ~ 1+Pois(16), max<<96
#define CSTR 16                  // cnt stride (ints): 1 counter per 64-B line

#define GB ((N_NODES + 63) / 64)     // 782 gemm blocks
#define FB8 ((ET + 2047) / 2048)     // 416 fill blocks (8 edges/thread)

typedef unsigned short u16;
typedef short bf16x8 __attribute__((ext_vector_type(8)));
typedef float f32x4 __attribute__((ext_vector_type(4)));
typedef u16 u16x8 __attribute__((ext_vector_type(8)));

__device__ __forceinline__ float lrelu(float x) { return x > 0.f ? x : NEG * x; }
__device__ __forceinline__ float bu2f(u16 u) { return __uint_as_float(((unsigned)u) << 16); }
__device__ __forceinline__ u16 f2bu(float f) {
    __hip_bfloat16 h = __float2bfloat16(f);
    return *reinterpret_cast<u16*>(&h);
}

__device__ __forceinline__ void edge_sd(const int* __restrict__ ei, int i, int& s, int& d) {
    if (i < N_EDGES) { s = ei[i]; d = ei[N_EDGES + i]; }
    else             { s = i - N_EDGES; d = s; }
}

// ---------------- fused: bucket fill (independent) + layer-1 GEMM via MFMA ----
// cnt padded to 1 counter / 64-B line; 8 edges per fill thread -> 8 independent
// atomics in flight per thread before any dependent store.
__global__ void __launch_bounds__(256) k_fill_gemm1(
        const int* __restrict__ ei, int* __restrict__ cnt, u16* __restrict__ esrc,
        const float* __restrict__ x, const float* __restrict__ W1,
        const float* __restrict__ a_s, const float* __restrict__ a_d,
        u16* __restrict__ h1b, float* __restrict__ al_s, float* __restrict__ al_d) {
    __shared__ u16 w1t[128 * 136];   // w1t[n][k], stride 136 (16B-aligned rows)
    int bid = blockIdx.x;
    int q;
    bool is_gemm;
    if (bid < 2 * FB8) { is_gemm = !(bid & 1); q = bid >> 1; }
    else               { is_gemm = true; q = FB8 + (bid - 2 * FB8); }
    if (!is_gemm) {
        // -------- fill role: 8 edges/thread --------
        int base = q * 2048 + threadIdx.x;
        int s[8], d[8], pos[8];
        bool v[8];
#pragma unroll
        for (int k = 0; k < 8; ++k) {
            int i = base + k * 256;
            v[k] = i < ET;
            if (v[k]) edge_sd(ei, i, s[k], d[k]);
        }
#pragma unroll
        for (int k = 0; k < 8; ++k)
            if (v[k]) pos[k] = atomicAdd(&cnt[d[k] * CSTR], 1);
#pragma unroll
        for (int k = 0; k < 8; ++k)
            if (v[k] && pos[k] < CAP) esrc[d[k] * CAP + pos[k]] = (u16)s[k];
        return;
    }
    // -------- gemm role --------
    int t = threadIdx.x;
    for (int it = 0; it < 64; ++it) {
        int idx = it * 256 + t;              // idx = k*128 + n
        int k = idx >> 7, n = idx & 127;
        w1t[n * 136 + k] = f2bu(W1[idx]);
    }
    __syncthreads();
    int wave = t >> 6, lane = t & 63;
    int col = lane & 15, quad = lane >> 4;
    int tb = q * 64 + wave * 16;
    union { bf16x8 v; u16 u[8]; } af[4];
    int anode = tb + col;
    bool aval = anode < N_NODES;
    const float* xr = x + (size_t)anode * F_IN + quad * 8;
#pragma unroll
    for (int kb = 0; kb < 4; ++kb) {
        float4 lo = aval ? ((const float4*)(xr + kb * 32))[0] : make_float4(0.f, 0.f, 0.f, 0.f);
        float4 hi = aval ? ((const float4*)(xr + kb * 32))[1] : make_float4(0.f, 0.f, 0.f, 0.f);
        af[kb].u[0] = f2bu(lo.x); af[kb].u[1] = f2bu(lo.y);
        af[kb].u[2] = f2bu(lo.z); af[kb].u[3] = f2bu(lo.w);
        af[kb].u[4] = f2bu(hi.x); af[kb].u[5] = f2bu(hi.y);
        af[kb].u[6] = f2bu(hi.z); af[kb].u[7] = f2bu(hi.w);
    }
    float ps[4][4] = {}, pd[4][4] = {};
#pragma unroll
    for (int nt = 0; nt < 8; ++nt) {
        f32x4 acc = {0.f, 0.f, 0.f, 0.f};
#pragma unroll
        for (int kb = 0; kb < 4; ++kb) {
            bf16x8 bf = *(const bf16x8*)&w1t[(nt * 16 + col) * 136 + kb * 32 + quad * 8];
            acc = __builtin_amdgcn_mfma_f32_16x16x32_bf16(af[kb].v, bf, acc, 0, 0, 0);
        }
        int feat = nt * 16 + col;
        float asv = a_s[feat], adv = a_d[feat];
        const int head = nt >> 1;
#pragma unroll
        for (int rr = 0; rr < 4; ++rr) {
            int node = tb + quad * 4 + rr;
            float v = acc[rr];
            if (node < N_NODES) h1b[(size_t)node * HH + feat] = f2bu(v);
            ps[rr][head] = fmaf(v, asv, ps[rr][head]);
            pd[rr][head] = fmaf(v, adv, pd[rr][head]);
        }
    }
#pragma unroll
    for (int rr = 0; rr < 4; ++rr)
#pragma unroll
        for (int h = 0; h < 4; ++h)
#pragma unroll
            for (int w = 1; w < 16; w <<= 1) {
                ps[rr][h] += __shfl_xor(ps[rr][h], w);
                pd[rr][h] += __shfl_xor(pd[rr][h], w);
            }
    if (col == 0) {
#pragma unroll
        for (int rr = 0; rr < 4; ++rr) {
            int node = tb + quad * 4 + rr;
            if (node < N_NODES) {
#pragma unroll
                for (int h = 0; h < 4; ++h) {
                    al_s[node * 4 + h] = ps[rr][h];
                    al_d[node * 4 + h] = pd[rr][h];
                }
            }
        }
    }
}

// ---------------- layer 1 aggregate + fused layer-2 GEMM + layer-2 logits ----------------
__global__ void __launch_bounds__(256) k_agg1(
        const u16* __restrict__ esrc, const int* __restrict__ cnt,
        const float* __restrict__ alS, const float* __restrict__ alD,
        const u16* __restrict__ h1b, const float* __restrict__ b1,
        const float* __restrict__ W2, const float* __restrict__ a_s2,
        const float* __restrict__ a_d2,
        u16* __restrict__ h2b, float* __restrict__ alS2, float* __restrict__ alD2) {
    __shared__ float wls[4][CAP * HEADS];        // 6 KB
    __shared__ int   sls[4][CAP];                // 1.5 KB
    __shared__ __align__(16) float rowf[4][HH];  // 2 KB
    __shared__ float w2t[NCLS * 132];            // 8.25 KB
    __shared__ float as2s[NCLS], ad2s[NCLS];
    int t = threadIdx.x;
    for (int idx = t; idx < F_IN * NCLS; idx += 256) {
        int f = idx >> 4, c = idx & 15;
        w2t[c * 132 + f] = W2[idx];
    }
    if (t < NCLS) { as2s[t] = a_s2[t]; ad2s[t] = a_d2[t]; }
    __syncthreads();
    int wave = t >> 6, lane = t & 63;
    int n = blockIdx.x * 4 + wave;               // grid = N/4 exactly
    int off = n * CAP;
    int deg = min(cnt[n * CSTR], CAP);           // deg >= 1 (self-loop)
    int dm1 = deg - 1;
    // ---- 1) single coalesced esrc read; sources live in registers (sreg) ----
    int sreg = (int)esrc[off + min(lane, dm1)];
    if (lane < deg) sls[wave][lane] = sreg;                 // covers e < 64
    for (int e = 64 + lane; e < deg; e += 64)               // deg > 64: ~never
        sls[wave][e] = (int)esrc[off + e];
    // ---- 2) phase-B deep prefetch: 6 x 4 edges = 24 in flight (clamped dups) ----
    int quarter = lane >> 4, fl = lane & 15;
    int hb = fl >> 2;
    u16x8 qf[6];
#pragma unroll
    for (int d = 0; d < 6; ++d) {
        int sp = __shfl(sreg, min(quarter + 4 * d, dm1));   // idx < 24 < 64
        qf[d] = ((const u16x8*)(h1b + (size_t)sp * HH))[fl];
    }
    // ---- 3) phase A: both alS gathers issued in parallel (deg<=32 covers ~100%) ----
    int slot = lane & 15, h = lane >> 4;
    int s0 = __shfl(sreg, min(slot, dm1));
    int s1 = __shfl(sreg, min(slot + 16, dm1));
    float av0 = alS[(size_t)s0 * 4 + h];
    float av1 = alS[(size_t)s1 * 4 + h];
    float ad = alD[n * 4 + h];
    float den = 0.f;
    if (slot < deg) {
        float wv = __expf(lrelu(av0 + ad));
        wls[wave][slot * 4 + h] = wv; den += wv;
    }
    if (slot + 16 < deg) {
        float wv = __expf(lrelu(av1 + ad));
        wls[wave][(slot + 16) * 4 + h] = wv; den += wv;
    }
    for (int e = slot + 32; e < deg; e += 16) {             // rare tail (P ~ 0.1%)
        int s = (int)esrc[off + e];
        float av = alS[(size_t)s * 4 + h];
        float wv = __expf(lrelu(av + ad));
        wls[wave][e * 4 + h] = wv; den += wv;
    }
#pragma unroll
    for (int w = 1; w < 16; w <<= 1) den += __shfl_xor(den, w);
    float inv = 1.f / den;
    // ---- 4) phase B consume: prefetched 24, then rare chained tail ----
    float invh = __shfl(inv, hb << 4);
    float acc[8] = {};
#pragma unroll
    for (int d = 0; d < 6; ++d) {
        int e = quarter + 4 * d;
        if (e < deg) {
            float a = wls[wave][e * 4 + hb] * invh;
#pragma unroll
            for (int j = 0; j < 8; ++j)
                acc[j] = fmaf(bu2f(qf[d][j]), a, acc[j]);
        }
    }
    for (int e = quarter + 24; e < deg; e += 4) {           // deg > 24: ~10% of nodes
        int sp = sls[wave][e];
        float a = wls[wave][e * 4 + hb] * invh;
        u16x8 qq = ((const u16x8*)(h1b + (size_t)sp * HH))[fl];
#pragma unroll
        for (int j = 0; j < 8; ++j)
            acc[j] = fmaf(bu2f(qq[j]), a, acc[j]);
    }
#pragma unroll
    for (int j = 0; j < 8; ++j) {
        acc[j] += __shfl_xor(acc[j], 16);
        acc[j] += __shfl_xor(acc[j], 32);
    }
    if (quarter == 0) {
        const float4* b4 = (const float4*)b1;
        float4 blo = b4[fl * 2], bhi = b4[fl * 2 + 1];
        float v[8];
        v[0] = acc[0] + blo.x; v[1] = acc[1] + blo.y;
        v[2] = acc[2] + blo.z; v[3] = acc[3] + blo.w;
        v[4] = acc[4] + bhi.x; v[5] = acc[5] + bhi.y;
        v[6] = acc[6] + bhi.z; v[7] = acc[7] + bhi.w;
#pragma unroll
        for (int j = 0; j < 8; ++j) v[j] = v[j] > 0.f ? v[j] : __expf(v[j]) - 1.f;
        ((float4*)&rowf[wave][0])[fl * 2]     = make_float4(v[0], v[1], v[2], v[3]);
        ((float4*)&rowf[wave][0])[fl * 2 + 1] = make_float4(v[4], v[5], v[6], v[7]);
    }
    // fused gemm2 (same wave -> LDS RAW ordered): f = 4i+q conflict-free
    int c = lane & 15, qq2 = lane >> 4;
    float h2acc = 0.f;
#pragma unroll
    for (int i = 0; i < 32; ++i) {
        int f = i * 4 + qq2;
        h2acc = fmaf(rowf[wave][f], w2t[c * 132 + f], h2acc);
    }
    h2acc += __shfl_xor(h2acc, 16);
    h2acc += __shfl_xor(h2acc, 32);
    if (lane < 16) h2b[(size_t)n * NCLS + lane] = f2bu(h2acc);
    float rs = h2acc * as2s[c], rd = h2acc * ad2s[c];
#pragma unroll
    for (int w = 1; w < 16; w <<= 1) { rs += __shfl_xor(rs, w); rd += __shfl_xor(rd, w); }
    if (lane == 0) { alS2[n] = rs; alD2[n] = rd; }
}

// ---------------- layer 2 aggregate + bias + log_softmax -> out ----------------
__global__ void __launch_bounds__(256) k_agg2(
        const u16* __restrict__ esrc, const int* __restrict__ cnt,
        const float* __restrict__ alS2, const float* __restrict__ alD2,
        const u16* __restrict__ h2b, const float* __restrict__ b2,
        float* __restrict__ out) {
    __shared__ float wls[4][CAP];   // 1.5 KB
    __shared__ int   sls[4][CAP];   // 1.5 KB
    int wave = threadIdx.x >> 6, lane = threadIdx.x & 63;
    int n = blockIdx.x * 4 + wave;
    int off = n * CAP;
    int deg = min(cnt[n * CSTR], CAP);
    int dm1 = deg - 1;
    int sub = lane >> 3, cp = lane & 7;
    // ---- 1) single coalesced esrc read ----
    int sreg = (int)esrc[off + min(lane, dm1)];
    // ---- 2) phase-B deep prefetch: 4 x 8 edges = 32 in flight (clamped dups) ----
    unsigned qf[4];
#pragma unroll
    for (int d = 0; d < 4; ++d) {
        int sp = __shfl(sreg, min(sub + 8 * d, dm1));       // idx < 32 < 64
        qf[d] = ((const unsigned*)(h2b + (size_t)sp * NCLS))[cp];
    }
    // ---- 3) phase A: lane e = lane, single gather ----
    float av = alS2[sreg];
    float ad = alD2[n];
    float den = 0.f;
    float wv = __expf(lrelu(av + ad));
    if (lane < deg) { wls[wave][lane] = wv; sls[wave][lane] = sreg; den = wv; }
    for (int e = 64 + lane; e < deg; e += 64) {             // deg > 64: ~never
        int s = (int)esrc[off + e];
        float a2 = alS2[s];
        float w2v = __expf(lrelu(a2 + ad));
        wls[wave][e] = w2v; sls[wave][e] = s; den += w2v;
    }
#pragma unroll
    for (int w = 1; w < 64; w <<= 1) den += __shfl_xor(den, w);
    float inv = 1.f / den;
    // ---- 4) phase B consume: prefetched 32, then rare chained tail ----
    float a0 = 0.f, a1 = 0.f;
#pragma unroll
    for (int d = 0; d < 4; ++d) {
        int e = sub + 8 * d;
        if (e < deg) {
            float al = wls[wave][e] * inv;
            a0 = fmaf(bu2f((u16)(qf[d] & 0xffffu)), al, a0);
            a1 = fmaf(bu2f((u16)(qf[d] >> 16)), al, a1);
        }
    }
    for (int e = sub + 32; e < deg; e += 8) {               // deg > 32: ~0.03%
        int s = sls[wave][e];
        float al = wls[wave][e] * inv;
        unsigned qq = ((const unsigned*)(h2b + (size_t)s * NCLS))[cp];
        a0 = fmaf(bu2f((u16)(qq & 0xffffu)), al, a0);
        a1 = fmaf(bu2f((u16)(qq >> 16)), al, a1);
    }
    a0 += __shfl_xor(a0, 8);  a1 += __shfl_xor(a1, 8);
    a0 += __shfl_xor(a0, 16); a1 += __shfl_xor(a1, 16);
    a0 += __shfl_xor(a0, 32); a1 += __shfl_xor(a1, 32);
    float v0 = a0 + b2[2 * cp], v1 = a1 + b2[2 * cp + 1];
    float mx = fmaxf(v0, v1);
#pragma unroll
    for (int w = 1; w < 8; w <<= 1) mx = fmaxf(mx, __shfl_xor(mx, w));
    float ex = __expf(v0 - mx) + __expf(v1 - mx);
#pragma unroll
    for (int w = 1; w < 8; w <<= 1) ex += __shfl_xor(ex, w);
    float lse = mx + __logf(ex);
    if (lane < 8) ((float2*)(out + (size_t)n * NCLS))[cp] = make_float2(v0 - lse, v1 - lse);
}

extern "C" void kernel_launch(void* const* d_in, const int* in_sizes, int n_in,
                              void* d_out, int out_size, void* d_ws, size_t ws_size,
                              hipStream_t stream) {
    const float* x   = (const float*)d_in[0];
    const int*   ei  = (const int*)d_in[1];
    const float* W1  = (const float*)d_in[2];
    const float* as1 = (const float*)d_in[3];
    const float* ad1 = (const float*)d_in[4];
    const float* b1  = (const float*)d_in[5];
    const float* W2  = (const float*)d_in[6];
    const float* as2 = (const float*)d_in[7];
    const float* ad2 = (const float*)d_in[8];
    const float* b2  = (const float*)d_in[9];
    float* out = (float*)d_out;
    char* ws = (char*)d_ws;

    u16*   h1b  = (u16*)  (ws);                 // N*128 bf16 = 12.8 MB
    float* alS1 = (float*)(ws + 12800000);      // N*4
    float* alD1 = (float*)(ws + 13600000);      // N*4
    u16*   h2b  = (u16*)  (ws + 14400000);      // N*16 bf16 = 1.6 MB
    float* alS2 = (float*)(ws + 16000000);      // N
    float* alD2 = (float*)(ws + 16200000);      // N
    int*   cnt  = (int*)  (ws + 16400000);      // N*CSTR ints = 3.2 MB (line-padded)
    u16*   esrc = (u16*)  (ws + 19600000);      // N*CAP u16 = 9.6 MB (total ~29.2 MB)

    hipMemsetAsync(cnt, 0, (size_t)N_NODES * CSTR * 4, stream);
    k_fill_gemm1<<<GB + FB8, 256, 0, stream>>>(ei, cnt, esrc,
                                               x, W1, as1, ad1, h1b, alS1, alD1);
    k_agg1<<<N_NODES / 4, 256, 0, stream>>>(esrc, cnt, alS1, alD1, h1b, b1,
                                            W2, as2, ad2, h2b, alS2, alD2);
    k_agg2<<<N_NODES / 4, 256, 0, stream>>>(esrc, cnt, alS2, alD2, h2b, b2, out);
}

// Round 9
// 196.627 us; speedup vs baseline: 1.1440x; 1.0626x over previous
//
#include <hip/hip_runtime.h>
#include <hip/hip_bf16.h>

#define N_NODES 50000
#define N_EDGES 800000
#define ET (N_EDGES + N_NODES)   // with self-loops
#define F_IN 128
#define HH 128                   // HEADS*HID
#define HEADS 4
#define HID 32
#define NCLS 16
#define NEG 0.2f
#define CAP 96                   // bucket capacity; deg ~ 1+Pois(16), max<<96
#define CSTR 16                  // cnt stride (ints): 1 counter per 64-B line

#define GB ((N_NODES + 63) / 64)     // 782 gemm blocks
#define FBX ((ET + 1023) / 1024)     // 831 fill blocks (4 edges/thread)

typedef unsigned short u16;
typedef short bf16x8 __attribute__((ext_vector_type(8)));
typedef float f32x4 __attribute__((ext_vector_type(4)));
typedef u16 u16x8 __attribute__((ext_vector_type(8)));

__device__ __forceinline__ float lrelu(float x) { return x > 0.f ? x : NEG * x; }
__device__ __forceinline__ float bu2f(u16 u) { return __uint_as_float(((unsigned)u) << 16); }
__device__ __forceinline__ u16 f2bu(float f) {
    __hip_bfloat16 h = __float2bfloat16(f);
    return *reinterpret_cast<u16*>(&h);
}

__device__ __forceinline__ void edge_sd(const int* __restrict__ ei, int i, int& s, int& d) {
    if (i < N_EDGES) { s = ei[i]; d = ei[N_EDGES + i]; }
    else             { s = i - N_EDGES; d = s; }
}

// ---------------- fused: bucket fill (independent) + layer-1 GEMM via MFMA ----
// LDS halved by N-splitting the W1 tile (two stage+compute phases) ->
// 17.4 KB/block -> 8 blocks/CU co-residency (was 4). Fill role = r6 shape:
// 4 edges/thread, line-padded cnt, 1:1 interleave with gemm blocks.
__global__ void __launch_bounds__(256) k_fill_gemm1(
        const int* __restrict__ ei, int* __restrict__ cnt, u16* __restrict__ esrc,
        const float* __restrict__ x, const float* __restrict__ W1,
        const float* __restrict__ a_s, const float* __restrict__ a_d,
        u16* __restrict__ h1b, float* __restrict__ al_s, float* __restrict__ al_d) {
    __shared__ u16 w1t[64 * 136];    // half of W1^T: [n-half][k], stride 136 (16B-aligned)
    int bid = blockIdx.x;
    bool is_gemm = ((bid & 1) == 0) && ((bid >> 1) < GB);
    if (!is_gemm) {
        // -------- fill role: 4 edges/thread --------
        int fid = bid - min((bid + 1) >> 1, GB);  // # gemm blocks before bid
        int base = fid * 1024 + threadIdx.x;
        int s[4], d[4], pos[4];
        bool v[4];
#pragma unroll
        for (int k = 0; k < 4; ++k) {
            int i = base + k * 256;
            v[k] = i < ET;
            if (v[k]) edge_sd(ei, i, s[k], d[k]);
        }
#pragma unroll
        for (int k = 0; k < 4; ++k)
            if (v[k]) pos[k] = atomicAdd(&cnt[d[k] * CSTR], 1);
#pragma unroll
        for (int k = 0; k < 4; ++k)
            if (v[k] && pos[k] < CAP) esrc[d[k] * CAP + pos[k]] = (u16)s[k];
        return;
    }
    // -------- gemm role (block id = bid>>1) --------
    int q = bid >> 1;
    int t = threadIdx.x;
    int wave = t >> 6, lane = t & 63;
    int col = lane & 15, quad = lane >> 4;
    int tb = q * 64 + wave * 16;
    union { bf16x8 v; u16 u[8]; } af[4];
    int anode = tb + col;
    bool aval = anode < N_NODES;
    const float* xr = x + (size_t)anode * F_IN + quad * 8;
#pragma unroll
    for (int kb = 0; kb < 4; ++kb) {
        float4 lo = aval ? ((const float4*)(xr + kb * 32))[0] : make_float4(0.f, 0.f, 0.f, 0.f);
        float4 hi = aval ? ((const float4*)(xr + kb * 32))[1] : make_float4(0.f, 0.f, 0.f, 0.f);
        af[kb].u[0] = f2bu(lo.x); af[kb].u[1] = f2bu(lo.y);
        af[kb].u[2] = f2bu(lo.z); af[kb].u[3] = f2bu(lo.w);
        af[kb].u[4] = f2bu(hi.x); af[kb].u[5] = f2bu(hi.y);
        af[kb].u[6] = f2bu(hi.z); af[kb].u[7] = f2bu(hi.w);
    }
    float ps[4][4] = {}, pd[4][4] = {};
#pragma unroll
    for (int h = 0; h < 2; ++h) {     // N-half: features [64h, 64h+64)
        if (h) __syncthreads();       // prev half's reads done before overwrite
        for (int it = 0; it < 32; ++it) {
            int lin = it * 256 + t;   // lin = k*64 + nn
            int k = lin >> 6, nn = lin & 63;
            w1t[nn * 136 + k] = f2bu(W1[k * 128 + 64 * h + nn]);
        }
        __syncthreads();
#pragma unroll
        for (int ntl = 0; ntl < 4; ++ntl) {
            int nt = h * 4 + ntl;
            f32x4 acc = {0.f, 0.f, 0.f, 0.f};
#pragma unroll
            for (int kb = 0; kb < 4; ++kb) {
                bf16x8 bf = *(const bf16x8*)&w1t[(ntl * 16 + col) * 136 + kb * 32 + quad * 8];
                acc = __builtin_amdgcn_mfma_f32_16x16x32_bf16(af[kb].v, bf, acc, 0, 0, 0);
            }
            int feat = nt * 16 + col;
            float asv = a_s[feat], adv = a_d[feat];
            const int head = nt >> 1;
#pragma unroll
            for (int rr = 0; rr < 4; ++rr) {
                int node = tb + quad * 4 + rr;
                float v = acc[rr];
                if (node < N_NODES) h1b[(size_t)node * HH + feat] = f2bu(v);
                ps[rr][head] = fmaf(v, asv, ps[rr][head]);
                pd[rr][head] = fmaf(v, adv, pd[rr][head]);
            }
        }
    }
#pragma unroll
    for (int rr = 0; rr < 4; ++rr)
#pragma unroll
        for (int h = 0; h < 4; ++h)
#pragma unroll
            for (int w = 1; w < 16; w <<= 1) {
                ps[rr][h] += __shfl_xor(ps[rr][h], w);
                pd[rr][h] += __shfl_xor(pd[rr][h], w);
            }
    if (col == 0) {
#pragma unroll
        for (int rr = 0; rr < 4; ++rr) {
            int node = tb + quad * 4 + rr;
            if (node < N_NODES) {
#pragma unroll
                for (int h = 0; h < 4; ++h) {
                    al_s[node * 4 + h] = ps[rr][h];
                    al_d[node * 4 + h] = pd[rr][h];
                }
            }
        }
    }
}

// ---------------- layer 1 aggregate + fused layer-2 GEMM + layer-2 logits ----------------
__global__ void __launch_bounds__(256) k_agg1(
        const u16* __restrict__ esrc, const int* __restrict__ cnt,
        const float* __restrict__ alS, const float* __restrict__ alD,
        const u16* __restrict__ h1b, const float* __restrict__ b1,
        const float* __restrict__ W2, const float* __restrict__ a_s2,
        const float* __restrict__ a_d2,
        u16* __restrict__ h2b, float* __restrict__ alS2, float* __restrict__ alD2) {
    __shared__ float wls[4][CAP * HEADS];        // 6 KB
    __shared__ int   sls[4][CAP];                // 1.5 KB
    __shared__ __align__(16) float rowf[4][HH];  // 2 KB
    __shared__ float w2t[NCLS * 132];            // 8.25 KB
    __shared__ float as2s[NCLS], ad2s[NCLS];
    int t = threadIdx.x;
    for (int idx = t; idx < F_IN * NCLS; idx += 256) {
        int f = idx >> 4, c = idx & 15;
        w2t[c * 132 + f] = W2[idx];
    }
    if (t < NCLS) { as2s[t] = a_s2[t]; ad2s[t] = a_d2[t]; }
    __syncthreads();
    int wave = t >> 6, lane = t & 63;
    int n = blockIdx.x * 4 + wave;               // grid = N/4 exactly
    int off = n * CAP;
    int deg = min(cnt[n * CSTR], CAP);           // deg >= 1 (self-loop)
    int dm1 = deg - 1;
    // ---- 1) single coalesced esrc read; sources live in registers (sreg) ----
    int sreg = (int)esrc[off + min(lane, dm1)];
    if (lane < deg) sls[wave][lane] = sreg;                 // covers e < 64
    for (int e = 64 + lane; e < deg; e += 64)               // deg > 64: ~never
        sls[wave][e] = (int)esrc[off + e];
    // ---- 2) phase-B deep prefetch: 6 x 4 edges = 24 in flight (clamped dups) ----
    int quarter = lane >> 4, fl = lane & 15;
    int hb = fl >> 2;
    u16x8 qf[6];
#pragma unroll
    for (int d = 0; d < 6; ++d) {
        int sp = __shfl(sreg, min(quarter + 4 * d, dm1));   // idx < 24 < 64
        qf[d] = ((const u16x8*)(h1b + (size_t)sp * HH))[fl];
    }
    // ---- 3) phase A: both alS gathers issued in parallel (deg<=32 covers ~100%) ----
    int slot = lane & 15, h = lane >> 4;
    int s0 = __shfl(sreg, min(slot, dm1));
    int s1 = __shfl(sreg, min(slot + 16, dm1));
    float av0 = alS[(size_t)s0 * 4 + h];
    float av1 = alS[(size_t)s1 * 4 + h];
    float ad = alD[n * 4 + h];
    float den = 0.f;
    if (slot < deg) {
        float wv = __expf(lrelu(av0 + ad));
        wls[wave][slot * 4 + h] = wv; den += wv;
    }
    if (slot + 16 < deg) {
        float wv = __expf(lrelu(av1 + ad));
        wls[wave][(slot + 16) * 4 + h] = wv; den += wv;
    }
    for (int e = slot + 32; e < deg; e += 16) {             // rare tail (P ~ 0.1%)
        int s = (int)esrc[off + e];
        float av = alS[(size_t)s * 4 + h];
        float wv = __expf(lrelu(av + ad));
        wls[wave][e * 4 + h] = wv; den += wv;
    }
#pragma unroll
    for (int w = 1; w < 16; w <<= 1) den += __shfl_xor(den, w);
    float inv = 1.f / den;
    // ---- 4) phase B consume: prefetched 24, then rare chained tail ----
    float invh = __shfl(inv, hb << 4);
    float acc[8] = {};
#pragma unroll
    for (int d = 0; d < 6; ++d) {
        int e = quarter + 4 * d;
        if (e < deg) {
            float a = wls[wave][e * 4 + hb] * invh;
#pragma unroll
            for (int j = 0; j < 8; ++j)
                acc[j] = fmaf(bu2f(qf[d][j]), a, acc[j]);
        }
    }
    for (int e = quarter + 24; e < deg; e += 4) {           // deg > 24: ~10% of nodes
        int sp = sls[wave][e];
        float a = wls[wave][e * 4 + hb] * invh;
        u16x8 qq = ((const u16x8*)(h1b + (size_t)sp * HH))[fl];
#pragma unroll
        for (int j = 0; j < 8; ++j)
            acc[j] = fmaf(bu2f(qq[j]), a, acc[j]);
    }
#pragma unroll
    for (int j = 0; j < 8; ++j) {
        acc[j] += __shfl_xor(acc[j], 16);
        acc[j] += __shfl_xor(acc[j], 32);
    }
    if (quarter == 0) {
        const float4* b4 = (const float4*)b1;
        float4 blo = b4[fl * 2], bhi = b4[fl * 2 + 1];
        float v[8];
        v[0] = acc[0] + blo.x; v[1] = acc[1] + blo.y;
        v[2] = acc[2] + blo.z; v[3] = acc[3] + blo.w;
        v[4] = acc[4] + bhi.x; v[5] = acc[5] + bhi.y;
        v[6] = acc[6] + bhi.z; v[7] = acc[7] + bhi.w;
#pragma unroll
        for (int j = 0; j < 8; ++j) v[j] = v[j] > 0.f ? v[j] : __expf(v[j]) - 1.f;
        ((float4*)&rowf[wave][0])[fl * 2]     = make_float4(v[0], v[1], v[2], v[3]);
        ((float4*)&rowf[wave][0])[fl * 2 + 1] = make_float4(v[4], v[5], v[6], v[7]);
    }
    // fused gemm2 (same wave -> LDS RAW ordered): f = 4i+q conflict-free
    int c = lane & 15, qq2 = lane >> 4;
    float h2acc = 0.f;
#pragma unroll
    for (int i = 0; i < 32; ++i) {
        int f = i * 4 + qq2;
        h2acc = fmaf(rowf[wave][f], w2t[c * 132 + f], h2acc);
    }
    h2acc += __shfl_xor(h2acc, 16);
    h2acc += __shfl_xor(h2acc, 32);
    if (lane < 16) h2b[(size_t)n * NCLS + lane] = f2bu(h2acc);
    float rs = h2acc * as2s[c], rd = h2acc * ad2s[c];
#pragma unroll
    for (int w = 1; w < 16; w <<= 1) { rs += __shfl_xor(rs, w); rd += __shfl_xor(rd, w); }
    if (lane == 0) { alS2[n] = rs; alD2[n] = rd; }
}

// ---------------- layer 2 aggregate + bias + log_softmax -> out ----------------
__global__ void __launch_bounds__(256) k_agg2(
        const u16* __restrict__ esrc, const int* __restrict__ cnt,
        const float* __restrict__ alS2, const float* __restrict__ alD2,
        const u16* __restrict__ h2b, const float* __restrict__ b2,
        float* __restrict__ out) {
    __shared__ float wls[4][CAP];   // 1.5 KB
    __shared__ int   sls[4][CAP];   // 1.5 KB
    int wave = threadIdx.x >> 6, lane = threadIdx.x & 63;
    int n = blockIdx.x * 4 + wave;
    int off = n * CAP;
    int deg = min(cnt[n * CSTR], CAP);
    int dm1 = deg - 1;
    int sub = lane >> 3, cp = lane & 7;
    // ---- 1) single coalesced esrc read ----
    int sreg = (int)esrc[off + min(lane, dm1)];
    // ---- 2) phase-B deep prefetch: 4 x 8 edges = 32 in flight (clamped dups) ----
    unsigned qf[4];
#pragma unroll
    for (int d = 0; d < 4; ++d) {
        int sp = __shfl(sreg, min(sub + 8 * d, dm1));       // idx < 32 < 64
        qf[d] = ((const unsigned*)(h2b + (size_t)sp * NCLS))[cp];
    }
    // ---- 3) phase A: lane e = lane, single gather ----
    float av = alS2[sreg];
    float ad = alD2[n];
    float den = 0.f;
    float wv = __expf(lrelu(av + ad));
    if (lane < deg) { wls[wave][lane] = wv; sls[wave][lane] = sreg; den = wv; }
    for (int e = 64 + lane; e < deg; e += 64) {             // deg > 64: ~never
        int s = (int)esrc[off + e];
        float a2 = alS2[s];
        float w2v = __expf(lrelu(a2 + ad));
        wls[wave][e] = w2v; sls[wave][e] = s; den += w2v;
    }
#pragma unroll
    for (int w = 1; w < 64; w <<= 1) den += __shfl_xor(den, w);
    float inv = 1.f / den;
    // ---- 4) phase B consume: prefetched 32, then rare chained tail ----
    float a0 = 0.f, a1 = 0.f;
#pragma unroll
    for (int d = 0; d < 4; ++d) {
        int e = sub + 8 * d;
        if (e < deg) {
            float al = wls[wave][e] * inv;
            a0 = fmaf(bu2f((u16)(qf[d] & 0xffffu)), al, a0);
            a1 = fmaf(bu2f((u16)(qf[d] >> 16)), al, a1);
        }
    }
    for (int e = sub + 32; e < deg; e += 8) {               // deg > 32: ~0.03%
        int s = sls[wave][e];
        float al = wls[wave][e] * inv;
        unsigned qq = ((const unsigned*)(h2b + (size_t)s * NCLS))[cp];
        a0 = fmaf(bu2f((u16)(qq & 0xffffu)), al, a0);
        a1 = fmaf(bu2f((u16)(qq >> 16)), al, a1);
    }
    a0 += __shfl_xor(a0, 8);  a1 += __shfl_xor(a1, 8);
    a0 += __shfl_xor(a0, 16); a1 += __shfl_xor(a1, 16);
    a0 += __shfl_xor(a0, 32); a1 += __shfl_xor(a1, 32);
    float v0 = a0 + b2[2 * cp], v1 = a1 + b2[2 * cp + 1];
    float mx = fmaxf(v0, v1);
#pragma unroll
    for (int w = 1; w < 8; w <<= 1) mx = fmaxf(mx, __shfl_xor(mx, w));
    float ex = __expf(v0 - mx) + __expf(v1 - mx);
#pragma unroll
    for (int w = 1; w < 8; w <<= 1) ex += __shfl_xor(ex, w);
    float lse = mx + __logf(ex);
    if (lane < 8) ((float2*)(out + (size_t)n * NCLS))[cp] = make_float2(v0 - lse, v1 - lse);
}

extern "C" void kernel_launch(void* const* d_in, const int* in_sizes, int n_in,
                              void* d_out, int out_size, void* d_ws, size_t ws_size,
                              hipStream_t stream) {
    const float* x   = (const float*)d_in[0];
    const int*   ei  = (const int*)d_in[1];
    const float* W1  = (const float*)d_in[2];
    const float* as1 = (const float*)d_in[3];
    const float* ad1 = (const float*)d_in[4];
    const float* b1  = (const float*)d_in[5];
    const float* W2  = (const float*)d_in[6];
    const float* as2 = (const float*)d_in[7];
    const float* ad2 = (const float*)d_in[8];
    const float* b2  = (const float*)d_in[9];
    float* out = (float*)d_out;
    char* ws = (char*)d_ws;

    u16*   h1b  = (u16*)  (ws);                 // N*128 bf16 = 12.8 MB
    float* alS1 = (float*)(ws + 12800000);      // N*4
    float* alD1 = (float*)(ws + 13600000);      // N*4
    u16*   h2b  = (u16*)  (ws + 14400000);      // N*16 bf16 = 1.6 MB
    float* alS2 = (float*)(ws + 16000000);      // N
    float* alD2 = (float*)(ws + 16200000);      // N
    int*   cnt  = (int*)  (ws + 16400000);      // N*CSTR ints = 3.2 MB (line-padded)
    u16*   esrc = (u16*)  (ws + 19600000);      // N*CAP u16 = 9.6 MB (total ~29.2 MB)

    hipMemsetAsync(cnt, 0, (size_t)N_NODES * CSTR * 4, stream);
    k_fill_gemm1<<<GB + FBX, 256, 0, stream>>>(ei, cnt, esrc,
                                               x, W1, as1, ad1, h1b, alS1, alD1);
    k_agg1<<<N_NODES / 4, 256, 0, stream>>>(esrc, cnt, alS1, alD1, h1b, b1,
                                            W2, as2, ad2, h2b, alS2, alD2);
    k_agg2<<<N_NODES / 4, 256, 0, stream>>>(esrc, cnt, alS2, alD2, h2b, b2, out);
}

// Round 10
// 195.055 us; speedup vs baseline: 1.1532x; 1.0081x over previous
//
#include <hip/hip_runtime.h>
#include <hip/hip_bf16.h>

#define N_NODES 50000
#define N_EDGES 800000
#define ET (N_EDGES + N_NODES)   // with self-loops
#define F_IN 128
#define HH 128                   // HEADS*HID
#define HEADS 4
#define HID 32
#define NCLS 16
#define NEG 0.2f
#define CAP 96                   // bucket capacity; deg ~ 1+Pois(16), max<<96
#define CSTR 16                  // cnt stride (ints): 1 counter per 64-B line

#define GB ((N_NODES + 63) / 64)     // 782 gemm blocks
#define FBX ((ET + 1023) / 1024)     // 831 fill blocks (4 edges/thread)

typedef unsigned short u16;
typedef short bf16x8 __attribute__((ext_vector_type(8)));
typedef float f32x4 __attribute__((ext_vector_type(4)));
typedef u16 u16x8 __attribute__((ext_vector_type(8)));

__device__ __forceinline__ float lrelu(float x) { return x > 0.f ? x : NEG * x; }
__device__ __forceinline__ float bu2f(u16 u) { return __uint_as_float(((unsigned)u) << 16); }
__device__ __forceinline__ u16 f2bu(float f) {
    __hip_bfloat16 h = __float2bfloat16(f);
    return *reinterpret_cast<u16*>(&h);
}

__device__ __forceinline__ void edge_sd(const int* __restrict__ ei, int i, int& s, int& d) {
    if (i < N_EDGES) { s = ei[i]; d = ei[N_EDGES + i]; }
    else             { s = i - N_EDGES; d = s; }
}

// ---------------- fused: bucket fill (independent) + layer-1 GEMM via MFMA ----
// LDS halved by N-splitting the W1 tile (two stage+compute phases) ->
// 17.4 KB/block -> 8 blocks/CU co-residency. Fill role: 4 edges/thread,
// line-padded cnt, 1:1 interleave with gemm blocks.
__global__ void __launch_bounds__(256) k_fill_gemm1(
        const int* __restrict__ ei, int* __restrict__ cnt, u16* __restrict__ esrc,
        const float* __restrict__ x, const float* __restrict__ W1,
        const float* __restrict__ a_s, const float* __restrict__ a_d,
        u16* __restrict__ h1b, float* __restrict__ al_s, float* __restrict__ al_d) {
    __shared__ u16 w1t[64 * 136];    // half of W1^T: [n-half][k], stride 136 (16B-aligned)
    int bid = blockIdx.x;
    bool is_gemm = ((bid & 1) == 0) && ((bid >> 1) < GB);
    if (!is_gemm) {
        // -------- fill role: 4 edges/thread --------
        int fid = bid - min((bid + 1) >> 1, GB);  // # gemm blocks before bid
        int base = fid * 1024 + threadIdx.x;
        int s[4], d[4], pos[4];
        bool v[4];
#pragma unroll
        for (int k = 0; k < 4; ++k) {
            int i = base + k * 256;
            v[k] = i < ET;
            if (v[k]) edge_sd(ei, i, s[k], d[k]);
        }
#pragma unroll
        for (int k = 0; k < 4; ++k)
            if (v[k]) pos[k] = atomicAdd(&cnt[d[k] * CSTR], 1);
#pragma unroll
        for (int k = 0; k < 4; ++k)
            if (v[k] && pos[k] < CAP) esrc[d[k] * CAP + pos[k]] = (u16)s[k];
        return;
    }
    // -------- gemm role (block id = bid>>1) --------
    int q = bid >> 1;
    int t = threadIdx.x;
    int wave = t >> 6, lane = t & 63;
    int col = lane & 15, quad = lane >> 4;
    int tb = q * 64 + wave * 16;
    union { bf16x8 v; u16 u[8]; } af[4];
    int anode = tb + col;
    bool aval = anode < N_NODES;
    const float* xr = x + (size_t)anode * F_IN + quad * 8;
#pragma unroll
    for (int kb = 0; kb < 4; ++kb) {
        float4 lo = aval ? ((const float4*)(xr + kb * 32))[0] : make_float4(0.f, 0.f, 0.f, 0.f);
        float4 hi = aval ? ((const float4*)(xr + kb * 32))[1] : make_float4(0.f, 0.f, 0.f, 0.f);
        af[kb].u[0] = f2bu(lo.x); af[kb].u[1] = f2bu(lo.y);
        af[kb].u[2] = f2bu(lo.z); af[kb].u[3] = f2bu(lo.w);
        af[kb].u[4] = f2bu(hi.x); af[kb].u[5] = f2bu(hi.y);
        af[kb].u[6] = f2bu(hi.z); af[kb].u[7] = f2bu(hi.w);
    }
    float ps[4][4] = {}, pd[4][4] = {};
#pragma unroll
    for (int h = 0; h < 2; ++h) {     // N-half: features [64h, 64h+64)
        if (h) __syncthreads();       // prev half's reads done before overwrite
        for (int it = 0; it < 32; ++it) {
            int lin = it * 256 + t;   // lin = k*64 + nn
            int k = lin >> 6, nn = lin & 63;
            w1t[nn * 136 + k] = f2bu(W1[k * 128 + 64 * h + nn]);
        }
        __syncthreads();
#pragma unroll
        for (int ntl = 0; ntl < 4; ++ntl) {
            int nt = h * 4 + ntl;
            f32x4 acc = {0.f, 0.f, 0.f, 0.f};
#pragma unroll
            for (int kb = 0; kb < 4; ++kb) {
                bf16x8 bf = *(const bf16x8*)&w1t[(ntl * 16 + col) * 136 + kb * 32 + quad * 8];
                acc = __builtin_amdgcn_mfma_f32_16x16x32_bf16(af[kb].v, bf, acc, 0, 0, 0);
            }
            int feat = nt * 16 + col;
            float asv = a_s[feat], adv = a_d[feat];
            const int head = nt >> 1;
#pragma unroll
            for (int rr = 0; rr < 4; ++rr) {
                int node = tb + quad * 4 + rr;
                float v = acc[rr];
                if (node < N_NODES) h1b[(size_t)node * HH + feat] = f2bu(v);
                ps[rr][head] = fmaf(v, asv, ps[rr][head]);
                pd[rr][head] = fmaf(v, adv, pd[rr][head]);
            }
        }
    }
#pragma unroll
    for (int rr = 0; rr < 4; ++rr)
#pragma unroll
        for (int h = 0; h < 4; ++h)
#pragma unroll
            for (int w = 1; w < 16; w <<= 1) {
                ps[rr][h] += __shfl_xor(ps[rr][h], w);
                pd[rr][h] += __shfl_xor(pd[rr][h], w);
            }
    if (col == 0) {
#pragma unroll
        for (int rr = 0; rr < 4; ++rr) {
            int node = tb + quad * 4 + rr;
            if (node < N_NODES) {
#pragma unroll
                for (int h = 0; h < 4; ++h) {
                    al_s[node * 4 + h] = ps[rr][h];
                    al_d[node * 4 + h] = pd[rr][h];
                }
            }
        }
    }
}

// ---------------- layer 1 aggregate + fused layer-2 GEMM + layer-2 logits ----------------
__global__ void __launch_bounds__(256) k_agg1(
        const u16* __restrict__ esrc, const int* __restrict__ cnt,
        const float* __restrict__ alS, const float* __restrict__ alD,
        const u16* __restrict__ h1b, const float* __restrict__ b1,
        const float* __restrict__ W2, const float* __restrict__ a_s2,
        const float* __restrict__ a_d2,
        u16* __restrict__ h2b, float* __restrict__ alS2, float* __restrict__ alD2) {
    __shared__ float wls[4][CAP * HEADS];        // 6 KB
    __shared__ int   sls[4][CAP];                // 1.5 KB
    __shared__ __align__(16) float rowf[4][HH];  // 2 KB
    __shared__ float w2t[NCLS * 132];            // 8.25 KB
    __shared__ float as2s[NCLS], ad2s[NCLS];
    int t = threadIdx.x;
    for (int idx = t; idx < F_IN * NCLS; idx += 256) {
        int f = idx >> 4, c = idx & 15;
        w2t[c * 132 + f] = W2[idx];
    }
    if (t < NCLS) { as2s[t] = a_s2[t]; ad2s[t] = a_d2[t]; }
    __syncthreads();
    int wave = t >> 6, lane = t & 63;
    int n = blockIdx.x * 4 + wave;               // grid = N/4 exactly
    int off = n * CAP;
    int deg = min(cnt[n * CSTR], CAP);           // deg >= 1 (self-loop)
    int dm1 = deg - 1;
    // ---- 1) single coalesced esrc read; sources live in registers (sreg) ----
    int sreg = (int)esrc[off + min(lane, dm1)];
    if (lane < deg) sls[wave][lane] = sreg;                 // covers e < 64
    for (int e = 64 + lane; e < deg; e += 64)               // deg > 64: ~never
        sls[wave][e] = (int)esrc[off + e];
    // ---- 2) phase-B deep prefetch: 6 x 4 edges = 24 in flight (clamped dups) ----
    int quarter = lane >> 4, fl = lane & 15;
    int hb = fl >> 2;
    u16x8 qf[6];
#pragma unroll
    for (int d = 0; d < 6; ++d) {
        int sp = __shfl(sreg, min(quarter + 4 * d, dm1));   // idx < 24 < 64
        qf[d] = ((const u16x8*)(h1b + (size_t)sp * HH))[fl];
    }
    // ---- 3) phase A: both alS gathers issued in parallel (deg<=32 covers ~100%) ----
    int slot = lane & 15, h = lane >> 4;
    int s0 = __shfl(sreg, min(slot, dm1));
    int s1 = __shfl(sreg, min(slot + 16, dm1));
    float av0 = alS[(size_t)s0 * 4 + h];
    float av1 = alS[(size_t)s1 * 4 + h];
    float ad = alD[n * 4 + h];
    float den = 0.f;
    if (slot < deg) {
        float wv = __expf(lrelu(av0 + ad));
        wls[wave][slot * 4 + h] = wv; den += wv;
    }
    if (slot + 16 < deg) {
        float wv = __expf(lrelu(av1 + ad));
        wls[wave][(slot + 16) * 4 + h] = wv; den += wv;
    }
    for (int e = slot + 32; e < deg; e += 16) {             // rare tail (P ~ 0.1%)
        int s = (int)esrc[off + e];
        float av = alS[(size_t)s * 4 + h];
        float wv = __expf(lrelu(av + ad));
        wls[wave][e * 4 + h] = wv; den += wv;
    }
#pragma unroll
    for (int w = 1; w < 16; w <<= 1) den += __shfl_xor(den, w);
    float inv = 1.f / den;
    // ---- 4) phase B consume: branchless select on the multiplier (no exec-mask
    //         toggles around the fma stream); then rare chained tail ----
    float invh = __shfl(inv, hb << 4);
    float acc[8] = {};
#pragma unroll
    for (int d = 0; d < 6; ++d) {
        int e = quarter + 4 * d;
        float a = e < deg ? wls[wave][e * 4 + hb] * invh : 0.f;
#pragma unroll
        for (int j = 0; j < 8; ++j)
            acc[j] = fmaf(bu2f(qf[d][j]), a, acc[j]);
    }
    for (int e = quarter + 24; e < deg; e += 4) {           // deg > 24: ~2% of nodes
        int sp = sls[wave][e];
        float a = wls[wave][e * 4 + hb] * invh;
        u16x8 qq = ((const u16x8*)(h1b + (size_t)sp * HH))[fl];
#pragma unroll
        for (int j = 0; j < 8; ++j)
            acc[j] = fmaf(bu2f(qq[j]), a, acc[j]);
    }
#pragma unroll
    for (int j = 0; j < 8; ++j) {
        acc[j] += __shfl_xor(acc[j], 16);
        acc[j] += __shfl_xor(acc[j], 32);
    }
    if (quarter == 0) {
        const float4* b4 = (const float4*)b1;
        float4 blo = b4[fl * 2], bhi = b4[fl * 2 + 1];
        float v[8];
        v[0] = acc[0] + blo.x; v[1] = acc[1] + blo.y;
        v[2] = acc[2] + blo.z; v[3] = acc[3] + blo.w;
        v[4] = acc[4] + bhi.x; v[5] = acc[5] + bhi.y;
        v[6] = acc[6] + bhi.z; v[7] = acc[7] + bhi.w;
#pragma unroll
        for (int j = 0; j < 8; ++j) v[j] = v[j] > 0.f ? v[j] : __expf(v[j]) - 1.f;
        ((float4*)&rowf[wave][0])[fl * 2]     = make_float4(v[0], v[1], v[2], v[3]);
        ((float4*)&rowf[wave][0])[fl * 2 + 1] = make_float4(v[4], v[5], v[6], v[7]);
    }
    // fused gemm2 (same wave -> LDS RAW ordered): f = 4i+q conflict-free
    int c = lane & 15, qq2 = lane >> 4;
    float h2acc = 0.f;
#pragma unroll
    for (int i = 0; i < 32; ++i) {
        int f = i * 4 + qq2;
        h2acc = fmaf(rowf[wave][f], w2t[c * 132 + f], h2acc);
    }
    h2acc += __shfl_xor(h2acc, 16);
    h2acc += __shfl_xor(h2acc, 32);
    if (lane < 16) h2b[(size_t)n * NCLS + lane] = f2bu(h2acc);
    float rs = h2acc * as2s[c], rd = h2acc * ad2s[c];
#pragma unroll
    for (int w = 1; w < 16; w <<= 1) { rs += __shfl_xor(rs, w); rd += __shfl_xor(rd, w); }
    if (lane == 0) { alS2[n] = rs; alD2[n] = rd; }
}

// ---------------- layer 2 aggregate + bias + log_softmax -> out ----------------
// 2 nodes per wave (32 lanes each): doubles node-level MLP per wave, halves
// wave count. All shuffles at width <= 16 stay within a half-wave.
__global__ void __launch_bounds__(256) k_agg2(
        const u16* __restrict__ esrc, const int* __restrict__ cnt,
        const float* __restrict__ alS2, const float* __restrict__ alD2,
        const u16* __restrict__ h2b, const float* __restrict__ b2,
        float* __restrict__ out) {
    __shared__ float wls[8][CAP];   // 3 KB
    __shared__ int   sls[8][CAP];   // 3 KB
    int wave = threadIdx.x >> 6, lane = threadIdx.x & 63;
    int half = lane >> 5, ll = lane & 31;
    int widx = wave * 2 + half;
    int n = blockIdx.x * 8 + widx;               // grid = N/8 exactly
    int off = n * CAP;
    int deg = min(cnt[n * CSTR], CAP);
    int dm1 = deg - 1;
    int sub = ll >> 3, cp = ll & 7;              // 4 edge-subs x 8 class-lanes
    // ---- 1) coalesced esrc read: 32 lanes per node ----
    int sreg = (int)esrc[off + min(ll, dm1)];
    // ---- 2) phase-B deep prefetch: 6 x 4 edges = 24 in flight (clamped dups) ----
    unsigned qf[6];
#pragma unroll
    for (int d = 0; d < 6; ++d) {
        int sp = __shfl(sreg, (half << 5) + min(sub + 4 * d, dm1));
        qf[d] = ((const unsigned*)(h2b + (size_t)sp * NCLS))[cp];
    }
    // ---- 3) phase A: e = ll (32 edges parallel, covers deg<=32 ~100%) ----
    float av = alS2[sreg];
    float ad = alD2[n];
    float den = 0.f;
    float wv = __expf(lrelu(av + ad));
    if (ll < deg) { wls[widx][ll] = wv; sls[widx][ll] = sreg; den = wv; }
    for (int e = 32 + ll; e < deg; e += 32) {    // deg > 32: ~0.03%
        int s = (int)esrc[off + e];
        float w2v = __expf(lrelu(alS2[s] + ad));
        wls[widx][e] = w2v; sls[widx][e] = s; den += w2v;
    }
#pragma unroll
    for (int w = 1; w < 32; w <<= 1) den += __shfl_xor(den, w);
    float inv = 1.f / den;
    // ---- 4) phase B consume: branchless multiplier select, then rare tail ----
    float a0 = 0.f, a1 = 0.f;
#pragma unroll
    for (int d = 0; d < 6; ++d) {
        int e = sub + 4 * d;
        float al = e < deg ? wls[widx][e] * inv : 0.f;
        a0 = fmaf(bu2f((u16)(qf[d] & 0xffffu)), al, a0);
        a1 = fmaf(bu2f((u16)(qf[d] >> 16)), al, a1);
    }
    for (int e = sub + 24; e < deg; e += 4) {    // deg > 24: ~2%
        int s = sls[widx][e];
        float al = wls[widx][e] * inv;
        unsigned qq = ((const unsigned*)(h2b + (size_t)s * NCLS))[cp];
        a0 = fmaf(bu2f((u16)(qq & 0xffffu)), al, a0);
        a1 = fmaf(bu2f((u16)(qq >> 16)), al, a1);
    }
    a0 += __shfl_xor(a0, 8);  a1 += __shfl_xor(a1, 8);
    a0 += __shfl_xor(a0, 16); a1 += __shfl_xor(a1, 16);
    float v0 = a0 + b2[2 * cp], v1 = a1 + b2[2 * cp + 1];
    float mx = fmaxf(v0, v1);
#pragma unroll
    for (int w = 1; w < 8; w <<= 1) mx = fmaxf(mx, __shfl_xor(mx, w));
    float ex = __expf(v0 - mx) + __expf(v1 - mx);
#pragma unroll
    for (int w = 1; w < 8; w <<= 1) ex += __shfl_xor(ex, w);
    float lse = mx + __logf(ex);
    if (ll < 8) ((float2*)(out + (size_t)n * NCLS))[cp] = make_float2(v0 - lse, v1 - lse);
}

extern "C" void kernel_launch(void* const* d_in, const int* in_sizes, int n_in,
                              void* d_out, int out_size, void* d_ws, size_t ws_size,
                              hipStream_t stream) {
    const float* x   = (const float*)d_in[0];
    const int*   ei  = (const int*)d_in[1];
    const float* W1  = (const float*)d_in[2];
    const float* as1 = (const float*)d_in[3];
    const float* ad1 = (const float*)d_in[4];
    const float* b1  = (const float*)d_in[5];
    const float* W2  = (const float*)d_in[6];
    const float* as2 = (const float*)d_in[7];
    const float* ad2 = (const float*)d_in[8];
    const float* b2  = (const float*)d_in[9];
    float* out = (float*)d_out;
    char* ws = (char*)d_ws;

    u16*   h1b  = (u16*)  (ws);                 // N*128 bf16 = 12.8 MB
    float* alS1 = (float*)(ws + 12800000);      // N*4
    float* alD1 = (float*)(ws + 13600000);      // N*4
    u16*   h2b  = (u16*)  (ws + 14400000);      // N*16 bf16 = 1.6 MB
    float* alS2 = (float*)(ws + 16000000);      // N
    float* alD2 = (float*)(ws + 16200000);      // N
    int*   cnt  = (int*)  (ws + 16400000);      // N*CSTR ints = 3.2 MB (line-padded)
    u16*   esrc = (u16*)  (ws + 19600000);      // N*CAP u16 = 9.6 MB (total ~29.2 MB)

    hipMemsetAsync(cnt, 0, (size_t)N_NODES * CSTR * 4, stream);
    k_fill_gemm1<<<GB + FBX, 256, 0, stream>>>(ei, cnt, esrc,
                                               x, W1, as1, ad1, h1b, alS1, alD1);
    k_agg1<<<N_NODES / 4, 256, 0, stream>>>(esrc, cnt, alS1, alD1, h1b, b1,
                                            W2, as2, ad2, h2b, alS2, alD2);
    k_agg2<<<N_NODES / 8, 256, 0, stream>>>(esrc, cnt, alS2, alD2, h2b, b2, out);
}

// Round 11
// 194.315 us; speedup vs baseline: 1.1576x; 1.0038x over previous
//
#include <hip/hip_runtime.h>
#include <hip/hip_bf16.h>

#define N_NODES 50000
#define N_EDGES 800000
#define ET (N_EDGES + N_NODES)   // with self-loops
#define F_IN 128
#define HH 128                   // HEADS*HID
#define HEADS 4
#define HID 32
#define NCLS 16
#define NEG 0.2f
#define CAP 96                   // bucket capacity; deg ~ 1+Pois(16), max<<96
#define CSTR 16                  // cnt stride (ints): 1 counter per 64-B line

#define GB ((N_NODES + 63) / 64)     // 782 gemm blocks
#define FBX ((ET + 1023) / 1024)     // 831 fill blocks (4 edges/thread)

typedef unsigned short u16;
typedef short bf16x8 __attribute__((ext_vector_type(8)));
typedef float f32x4 __attribute__((ext_vector_type(4)));

__device__ __forceinline__ float lrelu(float x) { return x > 0.f ? x : NEG * x; }
__device__ __forceinline__ float bu2f(u16 u) { return __uint_as_float(((unsigned)u) << 16); }
__device__ __forceinline__ u16 f2bu(float f) {
    __hip_bfloat16 h = __float2bfloat16(f);
    return *reinterpret_cast<u16*>(&h);
}

__device__ __forceinline__ void edge_sd(const int* __restrict__ ei, int i, int& s, int& d) {
    if (i < N_EDGES) { s = ei[i]; d = ei[N_EDGES + i]; }
    else             { s = i - N_EDGES; d = s; }
}

// ---------------- fused: bucket fill (independent) + layer-1 GEMM via MFMA ----
// LDS halved by N-splitting the W1 tile -> 17.4 KB -> 8 blocks/CU. Fill role:
// 4 edges/thread, line-padded cnt, 1:1 interleave with gemm blocks. (r9 state)
__global__ void __launch_bounds__(256) k_fill_gemm1(
        const int* __restrict__ ei, int* __restrict__ cnt, u16* __restrict__ esrc,
        const float* __restrict__ x, const float* __restrict__ W1,
        const float* __restrict__ a_s, const float* __restrict__ a_d,
        u16* __restrict__ h1b, float* __restrict__ al_s, float* __restrict__ al_d) {
    __shared__ u16 w1t[64 * 136];    // half of W1^T: [n-half][k], stride 136 (16B-aligned)
    int bid = blockIdx.x;
    bool is_gemm = ((bid & 1) == 0) && ((bid >> 1) < GB);
    if (!is_gemm) {
        // -------- fill role: 4 edges/thread --------
        int fid = bid - min((bid + 1) >> 1, GB);  // # gemm blocks before bid
        int base = fid * 1024 + threadIdx.x;
        int s[4], d[4], pos[4];
        bool v[4];
#pragma unroll
        for (int k = 0; k < 4; ++k) {
            int i = base + k * 256;
            v[k] = i < ET;
            if (v[k]) edge_sd(ei, i, s[k], d[k]);
        }
#pragma unroll
        for (int k = 0; k < 4; ++k)
            if (v[k]) pos[k] = atomicAdd(&cnt[d[k] * CSTR], 1);
#pragma unroll
        for (int k = 0; k < 4; ++k)
            if (v[k] && pos[k] < CAP) esrc[d[k] * CAP + pos[k]] = (u16)s[k];
        return;
    }
    // -------- gemm role (block id = bid>>1) --------
    int q = bid >> 1;
    int t = threadIdx.x;
    int wave = t >> 6, lane = t & 63;
    int col = lane & 15, quad = lane >> 4;
    int tb = q * 64 + wave * 16;
    union { bf16x8 v; u16 u[8]; } af[4];
    int anode = tb + col;
    bool aval = anode < N_NODES;
    const float* xr = x + (size_t)anode * F_IN + quad * 8;
#pragma unroll
    for (int kb = 0; kb < 4; ++kb) {
        float4 lo = aval ? ((const float4*)(xr + kb * 32))[0] : make_float4(0.f, 0.f, 0.f, 0.f);
        float4 hi = aval ? ((const float4*)(xr + kb * 32))[1] : make_float4(0.f, 0.f, 0.f, 0.f);
        af[kb].u[0] = f2bu(lo.x); af[kb].u[1] = f2bu(lo.y);
        af[kb].u[2] = f2bu(lo.z); af[kb].u[3] = f2bu(lo.w);
        af[kb].u[4] = f2bu(hi.x); af[kb].u[5] = f2bu(hi.y);
        af[kb].u[6] = f2bu(hi.z); af[kb].u[7] = f2bu(hi.w);
    }
    float ps[4][4] = {}, pd[4][4] = {};
#pragma unroll
    for (int h = 0; h < 2; ++h) {     // N-half: features [64h, 64h+64)
        if (h) __syncthreads();       // prev half's reads done before overwrite
        for (int it = 0; it < 32; ++it) {
            int lin = it * 256 + t;   // lin = k*64 + nn
            int k = lin >> 6, nn = lin & 63;
            w1t[nn * 136 + k] = f2bu(W1[k * 128 + 64 * h + nn]);
        }
        __syncthreads();
#pragma unroll
        for (int ntl = 0; ntl < 4; ++ntl) {
            int nt = h * 4 + ntl;
            f32x4 acc = {0.f, 0.f, 0.f, 0.f};
#pragma unroll
            for (int kb = 0; kb < 4; ++kb) {
                bf16x8 bf = *(const bf16x8*)&w1t[(ntl * 16 + col) * 136 + kb * 32 + quad * 8];
                acc = __builtin_amdgcn_mfma_f32_16x16x32_bf16(af[kb].v, bf, acc, 0, 0, 0);
            }
            int feat = nt * 16 + col;
            float asv = a_s[feat], adv = a_d[feat];
            const int head = nt >> 1;
#pragma unroll
            for (int rr = 0; rr < 4; ++rr) {
                int node = tb + quad * 4 + rr;
                float v = acc[rr];
                if (node < N_NODES) h1b[(size_t)node * HH + feat] = f2bu(v);
                ps[rr][head] = fmaf(v, asv, ps[rr][head]);
                pd[rr][head] = fmaf(v, adv, pd[rr][head]);
            }
        }
    }
#pragma unroll
    for (int rr = 0; rr < 4; ++rr)
#pragma unroll
        for (int h = 0; h < 4; ++h)
#pragma unroll
            for (int w = 1; w < 16; w <<= 1) {
                ps[rr][h] += __shfl_xor(ps[rr][h], w);
                pd[rr][h] += __shfl_xor(pd[rr][h], w);
            }
    if (col == 0) {
#pragma unroll
        for (int rr = 0; rr < 4; ++rr) {
            int node = tb + quad * 4 + rr;
            if (node < N_NODES) {
#pragma unroll
                for (int h = 0; h < 4; ++h) {
                    al_s[node * 4 + h] = ps[rr][h];
                    al_d[node * 4 + h] = pd[rr][h];
                }
            }
        }
    }
}

// ---------------- layer 1 aggregate + fused layer-2 GEMM + layer-2 logits ----------------
// 8 nodes/block (512 thr): w2t staging amortized 2x; 32-bit voffset addressing
// on all gathers; dword-wise bf16 expansion; float4 LDS reads in gemm2.
__global__ void __launch_bounds__(512) k_agg1(
        const u16* __restrict__ esrc, const int* __restrict__ cnt,
        const float* __restrict__ alS, const float* __restrict__ alD,
        const u16* __restrict__ h1b, const float* __restrict__ b1,
        const float* __restrict__ W2, const float* __restrict__ a_s2,
        const float* __restrict__ a_d2,
        u16* __restrict__ h2b, float* __restrict__ alS2, float* __restrict__ alD2) {
    __shared__ float wls[8][CAP * HEADS];        // 12 KB
    __shared__ int   sls[8][CAP];                // 3 KB
    __shared__ __align__(16) float rowf[8][HH];  // 4 KB
    __shared__ float w2t[NCLS * 132];            // 8.25 KB
    __shared__ float as2s[NCLS], ad2s[NCLS];
    int t = threadIdx.x;
    for (int idx = t; idx < F_IN * NCLS; idx += 512) {
        int f = idx >> 4, c = idx & 15;
        w2t[c * 132 + f] = W2[idx];
    }
    if (t < NCLS) { as2s[t] = a_s2[t]; ad2s[t] = a_d2[t]; }
    __syncthreads();
    int wave = t >> 6, lane = t & 63;
    int n = blockIdx.x * 8 + wave;               // grid = N/8 exactly
    unsigned off = (unsigned)n * CAP;
    int deg = min(cnt[n * CSTR], CAP);           // deg >= 1 (self-loop)
    int dm1 = deg - 1;
    // ---- 1) single coalesced esrc read; sources live in registers (sreg) ----
    int sreg = (int)esrc[off + min(lane, dm1)];
    if (lane < deg) sls[wave][lane] = sreg;                 // covers e < 64
    for (int e = 64 + lane; e < deg; e += 64)               // deg > 64: ~never
        sls[wave][e] = (int)esrc[off + e];
    // ---- 2) phase-B deep prefetch: 6 x 4 edges = 24 in flight (clamped dups;
    //         32-bit voffset addressing) ----
    int quarter = lane >> 4, fl = lane & 15;
    int hb = fl >> 2;
    uint4 qf[6];
#pragma unroll
    for (int d = 0; d < 6; ++d) {
        int sp = __shfl(sreg, min(quarter + 4 * d, dm1));   // idx < 24 < 64
        qf[d] = ((const uint4*)(h1b + ((unsigned)sp << 7)))[fl];
    }
    // ---- 3) phase A: both alS gathers issued in parallel (deg<=32 covers ~100%) ----
    int slot = lane & 15, h = lane >> 4;
    int s0 = __shfl(sreg, min(slot, dm1));
    int s1 = __shfl(sreg, min(slot + 16, dm1));
    float av0 = alS[((unsigned)s0 << 2) + h];
    float av1 = alS[((unsigned)s1 << 2) + h];
    float ad = alD[n * 4 + h];
    float den = 0.f;
    if (slot < deg) {
        float wv = __expf(lrelu(av0 + ad));
        wls[wave][slot * 4 + h] = wv; den += wv;
    }
    if (slot + 16 < deg) {
        float wv = __expf(lrelu(av1 + ad));
        wls[wave][(slot + 16) * 4 + h] = wv; den += wv;
    }
    for (int e = slot + 32; e < deg; e += 16) {             // rare tail (P ~ 0.1%)
        int s = (int)esrc[off + e];
        float av = alS[((unsigned)s << 2) + h];
        float wv = __expf(lrelu(av + ad));
        wls[wave][e * 4 + h] = wv; den += wv;
    }
#pragma unroll
    for (int w = 1; w < 16; w <<= 1) den += __shfl_xor(den, w);
    float inv = 1.f / den;
    // ---- 4) phase B consume: branchless multiplier select; dword-wise bf16
    //         expansion (d<<16 / d&0xffff0000); then rare chained tail ----
    float invh = __shfl(inv, hb << 4);
    float acc[8] = {};
#pragma unroll
    for (int d = 0; d < 6; ++d) {
        int e = quarter + 4 * d;
        float a = e < deg ? wls[wave][e * 4 + hb] * invh : 0.f;
        uint4 qd = qf[d];
        acc[0] = fmaf(__uint_as_float(qd.x << 16), a, acc[0]);
        acc[1] = fmaf(__uint_as_float(qd.x & 0xffff0000u), a, acc[1]);
        acc[2] = fmaf(__uint_as_float(qd.y << 16), a, acc[2]);
        acc[3] = fmaf(__uint_as_float(qd.y & 0xffff0000u), a, acc[3]);
        acc[4] = fmaf(__uint_as_float(qd.z << 16), a, acc[4]);
        acc[5] = fmaf(__uint_as_float(qd.z & 0xffff0000u), a, acc[5]);
        acc[6] = fmaf(__uint_as_float(qd.w << 16), a, acc[6]);
        acc[7] = fmaf(__uint_as_float(qd.w & 0xffff0000u), a, acc[7]);
    }
    for (int e = quarter + 24; e < deg; e += 4) {           // deg > 24: ~2% of nodes
        int sp = sls[wave][e];
        float a = wls[wave][e * 4 + hb] * invh;
        uint4 qd = ((const uint4*)(h1b + ((unsigned)sp << 7)))[fl];
        acc[0] = fmaf(__uint_as_float(qd.x << 16), a, acc[0]);
        acc[1] = fmaf(__uint_as_float(qd.x & 0xffff0000u), a, acc[1]);
        acc[2] = fmaf(__uint_as_float(qd.y << 16), a, acc[2]);
        acc[3] = fmaf(__uint_as_float(qd.y & 0xffff0000u), a, acc[3]);
        acc[4] = fmaf(__uint_as_float(qd.z << 16), a, acc[4]);
        acc[5] = fmaf(__uint_as_float(qd.z & 0xffff0000u), a, acc[5]);
        acc[6] = fmaf(__uint_as_float(qd.w << 16), a, acc[6]);
        acc[7] = fmaf(__uint_as_float(qd.w & 0xffff0000u), a, acc[7]);
    }
#pragma unroll
    for (int j = 0; j < 8; ++j) {
        acc[j] += __shfl_xor(acc[j], 16);
        acc[j] += __shfl_xor(acc[j], 32);
    }
    if (quarter == 0) {
        const float4* b4 = (const float4*)b1;
        float4 blo = b4[fl * 2], bhi = b4[fl * 2 + 1];
        float v[8];
        v[0] = acc[0] + blo.x; v[1] = acc[1] + blo.y;
        v[2] = acc[2] + blo.z; v[3] = acc[3] + blo.w;
        v[4] = acc[4] + bhi.x; v[5] = acc[5] + bhi.y;
        v[6] = acc[6] + bhi.z; v[7] = acc[7] + bhi.w;
#pragma unroll
        for (int j = 0; j < 8; ++j) v[j] = v[j] > 0.f ? v[j] : __expf(v[j]) - 1.f;
        ((float4*)&rowf[wave][0])[fl * 2]     = make_float4(v[0], v[1], v[2], v[3]);
        ((float4*)&rowf[wave][0])[fl * 2 + 1] = make_float4(v[4], v[5], v[6], v[7]);
    }
    // fused gemm2 (same wave -> LDS RAW ordered): float4 LDS reads.
    // rowf reads are same-address broadcasts within a q2 group (free);
    // w2t rows 16B-aligned (132 fl = 528 B = 33x16).
    int c = lane & 15, q2 = lane >> 4;
    const float4* ra = (const float4*)&rowf[wave][q2 * 32];
    const float4* wb = (const float4*)&w2t[c * 132 + q2 * 32];
    float h2acc = 0.f;
#pragma unroll
    for (int i = 0; i < 8; ++i) {
        float4 A = ra[i], B = wb[i];
        h2acc = fmaf(A.x, B.x, fmaf(A.y, B.y, fmaf(A.z, B.z, fmaf(A.w, B.w, h2acc))));
    }
    h2acc += __shfl_xor(h2acc, 16);
    h2acc += __shfl_xor(h2acc, 32);
    if (lane < 16) h2b[((unsigned)n << 4) + lane] = f2bu(h2acc);
    float rs = h2acc * as2s[c], rd = h2acc * ad2s[c];
#pragma unroll
    for (int w = 1; w < 16; w <<= 1) { rs += __shfl_xor(rs, w); rd += __shfl_xor(rd, w); }
    if (lane == 0) { alS2[n] = rs; alD2[n] = rd; }
}

// ---------------- layer 2 aggregate + bias + log_softmax -> out ----------------
// 2 nodes per wave (32 lanes each); 32-bit voffset addressing on gathers.
__global__ void __launch_bounds__(256) k_agg2(
        const u16* __restrict__ esrc, const int* __restrict__ cnt,
        const float* __restrict__ alS2, const float* __restrict__ alD2,
        const u16* __restrict__ h2b, const float* __restrict__ b2,
        float* __restrict__ out) {
    __shared__ float wls[8][CAP];   // 3 KB
    __shared__ int   sls[8][CAP];   // 3 KB
    int wave = threadIdx.x >> 6, lane = threadIdx.x & 63;
    int half = lane >> 5, ll = lane & 31;
    int widx = wave * 2 + half;
    int n = blockIdx.x * 8 + widx;               // grid = N/8 exactly
    unsigned off = (unsigned)n * CAP;
    int deg = min(cnt[n * CSTR], CAP);
    int dm1 = deg - 1;
    int sub = ll >> 3, cp = ll & 7;              // 4 edge-subs x 8 class-lanes
    // ---- 1) coalesced esrc read: 32 lanes per node ----
    int sreg = (int)esrc[off + min(ll, dm1)];
    // ---- 2) phase-B deep prefetch: 6 x 4 edges = 24 in flight (clamped dups) ----
    unsigned qf[6];
#pragma unroll
    for (int d = 0; d < 6; ++d) {
        int sp = __shfl(sreg, (half << 5) + min(sub + 4 * d, dm1));
        qf[d] = ((const unsigned*)(h2b + ((unsigned)sp << 4)))[cp];
    }
    // ---- 3) phase A: e = ll (32 edges parallel, covers deg<=32 ~100%) ----
    float av = alS2[sreg];
    float ad = alD2[n];
    float den = 0.f;
    float wv = __expf(lrelu(av + ad));
    if (ll < deg) { wls[widx][ll] = wv; sls[widx][ll] = sreg; den = wv; }
    for (int e = 32 + ll; e < deg; e += 32) {    // deg > 32: ~0.03%
        int s = (int)esrc[off + e];
        float w2v = __expf(lrelu(alS2[s] + ad));
        wls[widx][e] = w2v; sls[widx][e] = s; den += w2v;
    }
#pragma unroll
    for (int w = 1; w < 32; w <<= 1) den += __shfl_xor(den, w);
    float inv = 1.f / den;
    // ---- 4) phase B consume: branchless multiplier select, then rare tail ----
    float a0 = 0.f, a1 = 0.f;
#pragma unroll
    for (int d = 0; d < 6; ++d) {
        int e = sub + 4 * d;
        float al = e < deg ? wls[widx][e] * inv : 0.f;
        a0 = fmaf(__uint_as_float(qf[d] << 16), al, a0);
        a1 = fmaf(__uint_as_float(qf[d] & 0xffff0000u), al, a1);
    }
    for (int e = sub + 24; e < deg; e += 4) {    // deg > 24: ~2%
        int s = sls[widx][e];
        float al = wls[widx][e] * inv;
        unsigned qq = ((const unsigned*)(h2b + ((unsigned)s << 4)))[cp];
        a0 = fmaf(__uint_as_float(qq << 16), al, a0);
        a1 = fmaf(__uint_as_float(qq & 0xffff0000u), al, a1);
    }
    a0 += __shfl_xor(a0, 8);  a1 += __shfl_xor(a1, 8);
    a0 += __shfl_xor(a0, 16); a1 += __shfl_xor(a1, 16);
    float v0 = a0 + b2[2 * cp], v1 = a1 + b2[2 * cp + 1];
    float mx = fmaxf(v0, v1);
#pragma unroll
    for (int w = 1; w < 8; w <<= 1) mx = fmaxf(mx, __shfl_xor(mx, w));
    float ex = __expf(v0 - mx) + __expf(v1 - mx);
#pragma unroll
    for (int w = 1; w < 8; w <<= 1) ex += __shfl_xor(ex, w);
    float lse = mx + __logf(ex);
    if (ll < 8) ((float2*)(out + (size_t)n * NCLS))[cp] = make_float2(v0 - lse, v1 - lse);
}

extern "C" void kernel_launch(void* const* d_in, const int* in_sizes, int n_in,
                              void* d_out, int out_size, void* d_ws, size_t ws_size,
                              hipStream_t stream) {
    const float* x   = (const float*)d_in[0];
    const int*   ei  = (const int*)d_in[1];
    const float* W1  = (const float*)d_in[2];
    const float* as1 = (const float*)d_in[3];
    const float* ad1 = (const float*)d_in[4];
    const float* b1  = (const float*)d_in[5];
    const float* W2  = (const float*)d_in[6];
    const float* as2 = (const float*)d_in[7];
    const float* ad2 = (const float*)d_in[8];
    const float* b2  = (const float*)d_in[9];
    float* out = (float*)d_out;
    char* ws = (char*)d_ws;

    u16*   h1b  = (u16*)  (ws);                 // N*128 bf16 = 12.8 MB
    float* alS1 = (float*)(ws + 12800000);      // N*4
    float* alD1 = (float*)(ws + 13600000);      // N*4
    u16*   h2b  = (u16*)  (ws + 14400000);      // N*16 bf16 = 1.6 MB
    float* alS2 = (float*)(ws + 16000000);      // N
    float* alD2 = (float*)(ws + 16200000);      // N
    int*   cnt  = (int*)  (ws + 16400000);      // N*CSTR ints = 3.2 MB (line-padded)
    u16*   esrc = (u16*)  (ws + 19600000);      // N*CAP u16 = 9.6 MB (total ~29.2 MB)

    hipMemsetAsync(cnt, 0, (size_t)N_NODES * CSTR * 4, stream);
    k_fill_gemm1<<<GB + FBX, 256, 0, stream>>>(ei, cnt, esrc,
                                               x, W1, as1, ad1, h1b, alS1, alD1);
    k_agg1<<<N_NODES / 8, 512, 0, stream>>>(esrc, cnt, alS1, alD1, h1b, b1,
                                            W2, as2, ad2, h2b, alS2, alD2);
    k_agg2<<<N_NODES / 8, 256, 0, stream>>>(esrc, cnt, alS2, alD2, h2b, b2, out);
}